// Round 7
// baseline (3567.020 us; speedup 1.0000x reference)
//
#include <hip/hip_runtime.h>

#define NN 4096
#define TT 12
#define CC 32
#define WW 10            // T-2 windows
#define K3 12288         // 3*N
#define NCOL 640         // B*W*C
#define SA 4096.0f       // adj scale (2^12)
#define SX 1024.0f       // activation scale (2^10)
#define BM 48
#define BNH 320          // N-half per block
#define BK 32
#define NT (K3 / BK)     // 384 k-steps
#define ASTEP (768L * 512L)   // halves per k-step, A frag layout (768 m16-tiles)
#define BSTEP (40L * 512L)    // halves per k-step, B frag layout (40 col16-tiles)

typedef _Float16 half8 __attribute__((ext_vector_type(8)));
typedef float floatx4 __attribute__((ext_vector_type(4)));

// frag-native layout for an R-row × K-col matrix (R16 = R/16):
//   element (r, k) lives at ((k>>5)*R16 + (r>>4))*512 + ((r&15) + ((k>>3)&3)*16)*8 + (k&7)
// so an MFMA fragment (16 rows x 32 k) is 512 contiguous halves; lane l reads base + l*8.

// ---------------- adj fp32 -> fp16, scaled, frag-native ----------------
__global__ __launch_bounds__(256) void k_conv_adj(const float* __restrict__ adj,
                                                  _Float16* __restrict__ a16) {
    __shared__ _Float16 tile[16][520];
    int m16 = blockIdx.x;            // 0..767
    int kc  = blockIdx.y;            // 0..23 (512-wide k chunks)
    long m0 = (long)m16 * 16;
    long k0 = (long)kc * 512;
    int t = threadIdx.x;
    const float4* src = (const float4*)adj;
#pragma unroll
    for (int rep = 0; rep < 8; ++rep) {
        int idx = rep * 256 + t;
        int row = idx >> 7, c4 = idx & 127;
        float4 v = src[((m0 + row) * K3 + k0) / 4 + c4];
        tile[row][c4 * 4 + 0] = (_Float16)(v.x * SA);
        tile[row][c4 * 4 + 1] = (_Float16)(v.y * SA);
        tile[row][c4 * 4 + 2] = (_Float16)(v.z * SA);
        tile[row][c4 * 4 + 3] = (_Float16)(v.w * SA);
    }
    __syncthreads();
#pragma unroll
    for (int rep = 0; rep < 4; ++rep) {
        int slot = rep * 256 + t;
        int kt = slot >> 6, l = slot & 63;
        half8 h;
#pragma unroll
        for (int j = 0; j < 8; ++j)
            h[j] = tile[l & 15][kt * 32 + (l >> 4) * 8 + j];
        *(half8*)(a16 + ((long)(kc * 16 + kt) * 768 + m16) * 512 + l * 8) = h;
    }
}

// ---------------- build X0^T frag-native ----------------
__global__ void k_prep(const float* __restrict__ data, const float* __restrict__ temb,
                       const float* __restrict__ semb, _Float16* __restrict__ x0t) {
    __shared__ float sb[CC][64 + 1];
    int z = blockIdx.y;                 // 0..59
    int b = z / 30; int r = z % 30; int w = r / 3; int j3 = r % 3;
    int t = w + j3;
    int n0 = blockIdx.x * 64;
    int tid = threadIdx.x;
    for (int e = tid; e < 64 * CC; e += 256) {
        int nl = e >> 5, c = e & 31;
        float v = data[((long)(b * TT + t) * NN + n0 + nl) * CC + c]
                + temb[t * CC + c] + semb[(n0 + nl) * CC + c];
        sb[c][nl] = v;
    }
    __syncthreads();
    int bw = b * WW + w;
    int w4 = tid >> 6, l = tid & 63;
    int ct = w4 >> 1, kt = w4 & 1;
    int c = ct * 16 + (l & 15);
    int kb = kt * 32 + (l >> 4) * 8;
    half8 h;
#pragma unroll
    for (int j = 0; j < 8; ++j) h[j] = (_Float16)sb[c][kb + j];
    long k32 = (long)j3 * 128 + (n0 >> 5) + kt;
    *(half8*)(x0t + (k32 * 40 + bw * 2 + ct) * 512 + l * 8) = h;
}

// ---------------- fused GEMM + W-GEMM + GLU: frag-native, no LDS / no barriers ------
// Block: 256 thr / 4 waves; BM=48 rows x 320 cols (nh). Wave w owns cols wid*80..+80.
// All fragment loads are contiguous 1KB wave-loads; 2-deep register ping-pong.
template <int MODE>
__global__ __launch_bounds__(256, 3) void k_gemm_glu(
    const _Float16* __restrict__ A, const _Float16* __restrict__ BT,
    const float* __restrict__ Wt, const float* __restrict__ bias,
    _Float16* __restrict__ outH,
    const _Float16* __restrict__ x1, const _Float16* __restrict__ x2,
    float* __restrict__ outF,
    float invS, int mBase, int Mvalid)
{
    __shared__ float scr[BM * 161];          // 30.9 KB (2-pass epilogue scratch)
    __shared__ float WB[CC * 64 + 64];       // 8.4 KB
    const int SCRW = 161;

    int tid = threadIdx.x;
    int lane = tid & 63, wid = tid >> 6;

    // bijective XCD-chunked swizzle; (mt, nh) pairs adjacent -> same XCD shares A panel
    int nblk = gridDim.x;
    int q = nblk >> 3, r = nblk & 7;
    int xcd = blockIdx.x & 7, bi = blockIdx.x >> 3;
    int lin = (xcd < r ? xcd * (q + 1) : r * (q + 1) + (xcd - r) * q) + bi;
    int mt = lin >> 1, nh = lin & 1;
    long m0 = (long)mt * BM;                 // local output row base
    int n0 = nh * BNH;

    for (int e = tid; e < CC * 64; e += 256) WB[e] = Wt[e];
    if (tid < 64) WB[CC * 64 + tid] = bias[tid];
    // (first epilogue __syncthreads covers WB visibility)

    int m16b = (int)((mBase + m0) >> 4);
    const _Float16* aP0 = A + (long)(m16b + 0) * 512 + lane * 8;
    const _Float16* aP1 = A + (long)(m16b + 1) * 512 + lane * 8;
    const _Float16* aP2 = A + (long)(m16b + 2) * 512 + lane * 8;
    int c16 = (n0 >> 4) + wid * 5;
    const _Float16* bP0 = BT + (long)(c16 + 0) * 512 + lane * 8;
    const _Float16* bP1 = BT + (long)(c16 + 1) * 512 + lane * 8;
    const _Float16* bP2 = BT + (long)(c16 + 2) * 512 + lane * 8;
    const _Float16* bP3 = BT + (long)(c16 + 3) * 512 + lane * 8;
    const _Float16* bP4 = BT + (long)(c16 + 4) * 512 + lane * 8;

    floatx4 acc[3][5] = {};

#define LOAD_SET(sa0, sa1, sa2, sb0, sb1, sb2, sb3, sb4, OA, OB)   \
    do {                                                           \
        sa0 = *(const half8*)(aP0 + (OA));                         \
        sa1 = *(const half8*)(aP1 + (OA));                         \
        sa2 = *(const half8*)(aP2 + (OA));                         \
        sb0 = *(const half8*)(bP0 + (OB));                         \
        sb1 = *(const half8*)(bP1 + (OB));                         \
        sb2 = *(const half8*)(bP2 + (OB));                         \
        sb3 = *(const half8*)(bP3 + (OB));                         \
        sb4 = *(const half8*)(bP4 + (OB));                         \
    } while (0)

#define MFMA_SET(sa0, sa1, sa2, sb0, sb1, sb2, sb3, sb4)                              \
    do {                                                                              \
        acc[0][0] = __builtin_amdgcn_mfma_f32_16x16x32_f16(sa0, sb0, acc[0][0],0,0,0);\
        acc[0][1] = __builtin_amdgcn_mfma_f32_16x16x32_f16(sa0, sb1, acc[0][1],0,0,0);\
        acc[0][2] = __builtin_amdgcn_mfma_f32_16x16x32_f16(sa0, sb2, acc[0][2],0,0,0);\
        acc[0][3] = __builtin_amdgcn_mfma_f32_16x16x32_f16(sa0, sb3, acc[0][3],0,0,0);\
        acc[0][4] = __builtin_amdgcn_mfma_f32_16x16x32_f16(sa0, sb4, acc[0][4],0,0,0);\
        acc[1][0] = __builtin_amdgcn_mfma_f32_16x16x32_f16(sa1, sb0, acc[1][0],0,0,0);\
        acc[1][1] = __builtin_amdgcn_mfma_f32_16x16x32_f16(sa1, sb1, acc[1][1],0,0,0);\
        acc[1][2] = __builtin_amdgcn_mfma_f32_16x16x32_f16(sa1, sb2, acc[1][2],0,0,0);\
        acc[1][3] = __builtin_amdgcn_mfma_f32_16x16x32_f16(sa1, sb3, acc[1][3],0,0,0);\
        acc[1][4] = __builtin_amdgcn_mfma_f32_16x16x32_f16(sa1, sb4, acc[1][4],0,0,0);\
        acc[2][0] = __builtin_amdgcn_mfma_f32_16x16x32_f16(sa2, sb0, acc[2][0],0,0,0);\
        acc[2][1] = __builtin_amdgcn_mfma_f32_16x16x32_f16(sa2, sb1, acc[2][1],0,0,0);\
        acc[2][2] = __builtin_amdgcn_mfma_f32_16x16x32_f16(sa2, sb2, acc[2][2],0,0,0);\
        acc[2][3] = __builtin_amdgcn_mfma_f32_16x16x32_f16(sa2, sb3, acc[2][3],0,0,0);\
        acc[2][4] = __builtin_amdgcn_mfma_f32_16x16x32_f16(sa2, sb4, acc[2][4],0,0,0);\
    } while (0)

    half8 aA0, aA1, aA2, bA0, bA1, bA2, bA3, bA4;
    half8 aB0, aB1, aB2, bB0, bB1, bB2, bB3, bB4;

    LOAD_SET(aA0, aA1, aA2, bA0, bA1, bA2, bA3, bA4, 0, 0);
    LOAD_SET(aB0, aB1, aB2, bB0, bB1, bB2, bB3, bB4, ASTEP, BSTEP);
    aP0 += 2 * ASTEP; aP1 += 2 * ASTEP; aP2 += 2 * ASTEP;
    bP0 += 2 * BSTEP; bP1 += 2 * BSTEP; bP2 += 2 * BSTEP; bP3 += 2 * BSTEP; bP4 += 2 * BSTEP;

#pragma unroll 1
    for (int t = 0; t + 3 < NT; t += 2) {
        MFMA_SET(aA0, aA1, aA2, bA0, bA1, bA2, bA3, bA4);
        LOAD_SET(aA0, aA1, aA2, bA0, bA1, bA2, bA3, bA4, 0, 0);
        MFMA_SET(aB0, aB1, aB2, bB0, bB1, bB2, bB3, bB4);
        LOAD_SET(aB0, aB1, aB2, bB0, bB1, bB2, bB3, bB4, ASTEP, BSTEP);
        aP0 += 2 * ASTEP; aP1 += 2 * ASTEP; aP2 += 2 * ASTEP;
        bP0 += 2 * BSTEP; bP1 += 2 * BSTEP; bP2 += 2 * BSTEP; bP3 += 2 * BSTEP; bP4 += 2 * BSTEP;
    }
    MFMA_SET(aA0, aA1, aA2, bA0, bA1, bA2, bA3, bA4);
    MFMA_SET(aB0, aB1, aB2, bB0, bB1, bB2, bB3, bB4);
#undef LOAD_SET
#undef MFMA_SET

    // -------- epilogue: 2-pass LDS transpose + tiny W-GEMM + GLU --------
    int rb = (lane >> 4) * 4, cb = lane & 15;

#pragma unroll 1
    for (int h = 0; h < 2; ++h) {
        __syncthreads();
        if ((wid >> 1) == h) {           // waves 2h, 2h+1 own cols [h*160, +160)
            int wl = wid & 1;
#pragma unroll
            for (int ms = 0; ms < 3; ++ms)
#pragma unroll
                for (int ns = 0; ns < 5; ++ns)
#pragma unroll
                    for (int i = 0; i < 4; ++i)
                        scr[(ms * 16 + rb + i) * SCRW + wl * 80 + ns * 16 + cb] = acc[ms][ns][i];
        }
        __syncthreads();
        if (tid < 240) {
            int row = tid % 48;
            int bl = tid / 48;           // 0..4
            int bw = nh * 10 + h * 5 + bl;
            long m = m0 + row;
            float g[CC];
#pragma unroll
            for (int c = 0; c < CC; ++c) g[c] = scr[row * SCRW + bl * 32 + c] * invS;
            float y[64];
#pragma unroll
            for (int o = 0; o < 64; ++o) y[o] = WB[CC * 64 + o];
#pragma unroll
            for (int c = 0; c < CC; ++c) {
                float gv = g[c];
#pragma unroll
                for (int o = 0; o < 64; ++o) y[o] = fmaf(gv, WB[c * 64 + o], y[o]);
            }
            if (MODE == 0) {
                // write X^T frag-native: col = bw*32+c, k = m
                long k32 = m >> 5;
                int kb16 = ((int)(m >> 3) & 3) * 16;
                int kj = (int)(m & 7);
#pragma unroll
                for (int c = 0; c < CC; ++c) {
                    float rr = y[c] * (1.f / (1.f + __expf(-y[c + 32])));
                    long dst = ((k32 * 40) + (bw * 2 + (c >> 4))) * 512
                             + ((c & 15) + kb16) * 8 + kj;
                    outH[dst] = (_Float16)(rr * SX);
                }
            } else {
                if (m < Mvalid) {
                    long kk = NN + m;
                    long k32 = kk >> 5;
                    int kb16 = ((int)(kk >> 3) & 3) * 16;
                    int kj = (int)(kk & 7);
                    float res[CC];
#pragma unroll
                    for (int c = 0; c < CC; ++c) {
                        float rr = y[c] * (1.f / (1.f + __expf(-y[c + 32])));
                        long idx = ((k32 * 40) + (bw * 2 + (c >> 4))) * 512
                                 + ((c & 15) + kb16) * 8 + kj;
                        float v1 = (float)x1[idx] * (1.f / SX);
                        float v2 = (float)x2[idx] * (1.f / SX);
                        res[c] = fmaxf(rr, fmaxf(v1, v2));
                    }
                    float4* op = (float4*)(outF + ((long)bw * NN + m) * CC);
#pragma unroll
                    for (int qv = 0; qv < CC / 4; ++qv)
                        op[qv] = make_float4(res[qv * 4 + 0], res[qv * 4 + 1],
                                             res[qv * 4 + 2], res[qv * 4 + 3]);
                }
            }
        }
    }
}

extern "C" void kernel_launch(void* const* d_in, const int* in_sizes, int n_in,
                              void* d_out, int out_size, void* d_ws, size_t ws_size,
                              hipStream_t stream)
{
    const float* data = (const float*)d_in[0];
    const float* adj  = (const float*)d_in[1];
    const float* temb = (const float*)d_in[2];
    const float* semb = (const float*)d_in[3];
    const float* W0 = (const float*)d_in[4];
    const float* b0 = (const float*)d_in[5];
    const float* W1 = (const float*)d_in[6];
    const float* b1 = (const float*)d_in[7];
    const float* W2 = (const float*)d_in[8];
    const float* b2 = (const float*)d_in[9];
    float* out = (float*)d_out;
    (void)ws_size; (void)in_sizes; (void)n_in; (void)out_size;

    char* ws = (char*)d_ws;
    _Float16* A16 = (_Float16*)ws;  ws += (size_t)K3 * K3 * 2;        // 302 MB
    _Float16* X0  = (_Float16*)ws;  ws += (size_t)NCOL * K3 * 2;      // 15.7 MB
    _Float16* X1  = (_Float16*)ws;  ws += (size_t)NCOL * K3 * 2;
    _Float16* X2  = (_Float16*)ws;  ws += (size_t)NCOL * K3 * 2;

    k_conv_adj<<<dim3(768, 24), 256, 0, stream>>>(adj, A16);
    k_prep<<<dim3(64, 60), 256, 0, stream>>>(data, temb, semb, X0);

    // layer 1: 256 m-tiles x 2 n-halves
    k_gemm_glu<0><<<512, 256, 0, stream>>>(A16, X0, W0, b0, X1,
                                           nullptr, nullptr, nullptr, 1.f / SA, 0, K3);
    // layer 2
    k_gemm_glu<0><<<512, 256, 0, stream>>>(A16, X1, W1, b1, X2,
                                           nullptr, nullptr, nullptr, 1.f / (SA * SX), 0, K3);
    // layer 3: middle N rows of adj; fused GLU + 3-way max + final layout
    k_gemm_glu<1><<<172, 256, 0, stream>>>(A16, X2, W2, b2, nullptr,
                                           X1, X2, out, 1.f / (SA * SX), NN, NN);
}

// Round 8
// 1281.365 us; speedup vs baseline: 2.7838x; 2.7838x over previous
//
#include <hip/hip_runtime.h>

#define NN 4096
#define TT 12
#define CC 32
#define WW 10            // T-2 windows
#define K3 12288         // 3*N
#define NCOL 640         // B*W*C
#define SA 4096.0f       // adj scale (2^12)
#define SX 1024.0f       // activation scale (2^10)
#define BM 96
#define BNH 320          // N-half per block
#define BK 32
#define NT (K3 / BK)     // 384 k-steps
#define ASTEP (768L * 512L)   // halves per k-step in A frag layout (768 m16-tiles)
#define BSTEP (40L * 512L)    // halves per k-step in B frag layout (40 col16-tiles)

typedef _Float16 half8 __attribute__((ext_vector_type(8)));
typedef float floatx4 __attribute__((ext_vector_type(4)));

// frag-native layout for an R-row × K-col matrix (R16 = R/16):
//   element (r, k) -> ((k>>5)*R16 + (r>>4))*512 + ((r&15) + ((k>>3)&3)*16)*8 + (k&7)
// an MFMA fragment (16 rows x 32 k) = 512 contiguous halves; lane l reads base + l*8.

// ---------------- adj fp32 -> fp16, scaled, frag-native ----------------
__global__ __launch_bounds__(256) void k_conv_adj(const float* __restrict__ adj,
                                                  _Float16* __restrict__ a16) {
    __shared__ _Float16 tile[16][520];
    int m16 = blockIdx.x;            // 0..767
    int kc  = blockIdx.y;            // 0..23 (512-wide k chunks)
    long m0 = (long)m16 * 16;
    long k0 = (long)kc * 512;
    int t = threadIdx.x;
    const float4* src = (const float4*)adj;
#pragma unroll
    for (int rep = 0; rep < 8; ++rep) {
        int idx = rep * 256 + t;
        int row = idx >> 7, c4 = idx & 127;
        float4 v = src[((m0 + row) * K3 + k0) / 4 + c4];
        tile[row][c4 * 4 + 0] = (_Float16)(v.x * SA);
        tile[row][c4 * 4 + 1] = (_Float16)(v.y * SA);
        tile[row][c4 * 4 + 2] = (_Float16)(v.z * SA);
        tile[row][c4 * 4 + 3] = (_Float16)(v.w * SA);
    }
    __syncthreads();
#pragma unroll
    for (int rep = 0; rep < 4; ++rep) {
        int slot = rep * 256 + t;
        int kt = slot >> 6, l = slot & 63;
        half8 h;
#pragma unroll
        for (int j = 0; j < 8; ++j)
            h[j] = tile[l & 15][kt * 32 + (l >> 4) * 8 + j];
        *(half8*)(a16 + ((long)(kc * 16 + kt) * 768 + m16) * 512 + l * 8) = h;
    }
}

// ---------------- build X0^T frag-native ----------------
__global__ void k_prep(const float* __restrict__ data, const float* __restrict__ temb,
                       const float* __restrict__ semb, _Float16* __restrict__ x0t) {
    __shared__ float sb[CC][64 + 1];
    int z = blockIdx.y;                 // 0..59
    int b = z / 30; int r = z % 30; int w = r / 3; int j3 = r % 3;
    int t = w + j3;
    int n0 = blockIdx.x * 64;
    int tid = threadIdx.x;
    for (int e = tid; e < 64 * CC; e += 256) {
        int nl = e >> 5, c = e & 31;
        float v = data[((long)(b * TT + t) * NN + n0 + nl) * CC + c]
                + temb[t * CC + c] + semb[(n0 + nl) * CC + c];
        sb[c][nl] = v;
    }
    __syncthreads();
    int bw = b * WW + w;
    int w4 = tid >> 6, l = tid & 63;
    int ct = w4 >> 1, kt = w4 & 1;
    int c = ct * 16 + (l & 15);
    int kb = kt * 32 + (l >> 4) * 8;
    half8 h;
#pragma unroll
    for (int j = 0; j < 8; ++j) h[j] = (_Float16)sb[c][kb + j];
    long k32 = (long)j3 * 128 + (n0 >> 5) + kt;
    *(half8*)(x0t + (k32 * 40 + bw * 2 + ct) * 512 + l * 8) = h;
}

// ---------------- fused GEMM + W-GEMM + GLU: frag-native, no LDS / no barriers ------
// Block: 512 thr / 8 waves (2 m-groups x 4 n-groups); block tile 96 x 320.
// Wave (wm, wn) owns rows wm*48..+48, cols n0+wn*80..+80 (3x5 fragments).
// All fragment loads contiguous 1KB wave-loads; 2-deep register ping-pong; no spill
// (launch_bounds(512,1) -> 256-VGPR cap; demand ~150).
template <int MODE>
__global__ __launch_bounds__(512, 1) void k_gemm_glu(
    const _Float16* __restrict__ A, const _Float16* __restrict__ BT,
    const float* __restrict__ Wt, const float* __restrict__ bias,
    _Float16* __restrict__ outH,
    const _Float16* __restrict__ x1, const _Float16* __restrict__ x2,
    float* __restrict__ outF,
    float invS, int mBase, int Mvalid)
{
    __shared__ float scr[BM * 321];          // 123.3 KB epilogue transpose scratch
    __shared__ float WB[CC * 64 + 64];       // 8.4 KB
    const int SCRW = 321;

    int tid = threadIdx.x;
    int lane = tid & 63, wid = tid >> 6;
    int wm = wid >> 2, wn = wid & 3;

    // bijective XCD-chunked swizzle; consecutive lin on one XCD -> L2 dedups B
    int nblk = gridDim.x;
    int q = nblk >> 3, r = nblk & 7;
    int xcd = blockIdx.x & 7, bi = blockIdx.x >> 3;
    int lin = (xcd < r ? xcd * (q + 1) : r * (q + 1) + (xcd - r) * q) + bi;
    int mt = lin >> 1, nh = lin & 1;
    long m0 = (long)mt * BM;                 // local output row base
    int n0 = nh * BNH;

    for (int e = tid; e < CC * 64; e += 512) WB[e] = Wt[e];
    if (tid < 64) WB[CC * 64 + tid] = bias[tid];
    // (epilogue __syncthreads covers WB visibility)

    int m16b = (int)((mBase + m0) >> 4) + wm * 3;
    const _Float16* aP0 = A + (long)(m16b + 0) * 512 + lane * 8;
    const _Float16* aP1 = A + (long)(m16b + 1) * 512 + lane * 8;
    const _Float16* aP2 = A + (long)(m16b + 2) * 512 + lane * 8;
    int c16 = (n0 >> 4) + wn * 5;
    const _Float16* bP0 = BT + (long)(c16 + 0) * 512 + lane * 8;
    const _Float16* bP1 = BT + (long)(c16 + 1) * 512 + lane * 8;
    const _Float16* bP2 = BT + (long)(c16 + 2) * 512 + lane * 8;
    const _Float16* bP3 = BT + (long)(c16 + 3) * 512 + lane * 8;
    const _Float16* bP4 = BT + (long)(c16 + 4) * 512 + lane * 8;

    floatx4 acc[3][5] = {};

#define LOAD_SET(sa0, sa1, sa2, sb0, sb1, sb2, sb3, sb4, OA, OB)   \
    do {                                                           \
        sa0 = *(const half8*)(aP0 + (OA));                         \
        sa1 = *(const half8*)(aP1 + (OA));                         \
        sa2 = *(const half8*)(aP2 + (OA));                         \
        sb0 = *(const half8*)(bP0 + (OB));                         \
        sb1 = *(const half8*)(bP1 + (OB));                         \
        sb2 = *(const half8*)(bP2 + (OB));                         \
        sb3 = *(const half8*)(bP3 + (OB));                         \
        sb4 = *(const half8*)(bP4 + (OB));                         \
    } while (0)

#define MFMA_SET(sa0, sa1, sa2, sb0, sb1, sb2, sb3, sb4)                              \
    do {                                                                              \
        acc[0][0] = __builtin_amdgcn_mfma_f32_16x16x32_f16(sa0, sb0, acc[0][0],0,0,0);\
        acc[0][1] = __builtin_amdgcn_mfma_f32_16x16x32_f16(sa0, sb1, acc[0][1],0,0,0);\
        acc[0][2] = __builtin_amdgcn_mfma_f32_16x16x32_f16(sa0, sb2, acc[0][2],0,0,0);\
        acc[0][3] = __builtin_amdgcn_mfma_f32_16x16x32_f16(sa0, sb3, acc[0][3],0,0,0);\
        acc[0][4] = __builtin_amdgcn_mfma_f32_16x16x32_f16(sa0, sb4, acc[0][4],0,0,0);\
        acc[1][0] = __builtin_amdgcn_mfma_f32_16x16x32_f16(sa1, sb0, acc[1][0],0,0,0);\
        acc[1][1] = __builtin_amdgcn_mfma_f32_16x16x32_f16(sa1, sb1, acc[1][1],0,0,0);\
        acc[1][2] = __builtin_amdgcn_mfma_f32_16x16x32_f16(sa1, sb2, acc[1][2],0,0,0);\
        acc[1][3] = __builtin_amdgcn_mfma_f32_16x16x32_f16(sa1, sb3, acc[1][3],0,0,0);\
        acc[1][4] = __builtin_amdgcn_mfma_f32_16x16x32_f16(sa1, sb4, acc[1][4],0,0,0);\
        acc[2][0] = __builtin_amdgcn_mfma_f32_16x16x32_f16(sa2, sb0, acc[2][0],0,0,0);\
        acc[2][1] = __builtin_amdgcn_mfma_f32_16x16x32_f16(sa2, sb1, acc[2][1],0,0,0);\
        acc[2][2] = __builtin_amdgcn_mfma_f32_16x16x32_f16(sa2, sb2, acc[2][2],0,0,0);\
        acc[2][3] = __builtin_amdgcn_mfma_f32_16x16x32_f16(sa2, sb3, acc[2][3],0,0,0);\
        acc[2][4] = __builtin_amdgcn_mfma_f32_16x16x32_f16(sa2, sb4, acc[2][4],0,0,0);\
    } while (0)

    half8 aA0, aA1, aA2, bA0, bA1, bA2, bA3, bA4;
    half8 aB0, aB1, aB2, bB0, bB1, bB2, bB3, bB4;

    LOAD_SET(aA0, aA1, aA2, bA0, bA1, bA2, bA3, bA4, 0, 0);
    LOAD_SET(aB0, aB1, aB2, bB0, bB1, bB2, bB3, bB4, ASTEP, BSTEP);
    aP0 += 2 * ASTEP; aP1 += 2 * ASTEP; aP2 += 2 * ASTEP;
    bP0 += 2 * BSTEP; bP1 += 2 * BSTEP; bP2 += 2 * BSTEP; bP3 += 2 * BSTEP; bP4 += 2 * BSTEP;

#pragma unroll 1
    for (int t = 0; t + 3 < NT; t += 2) {
        MFMA_SET(aA0, aA1, aA2, bA0, bA1, bA2, bA3, bA4);
        LOAD_SET(aA0, aA1, aA2, bA0, bA1, bA2, bA3, bA4, 0, 0);
        MFMA_SET(aB0, aB1, aB2, bB0, bB1, bB2, bB3, bB4);
        LOAD_SET(aB0, aB1, aB2, bB0, bB1, bB2, bB3, bB4, ASTEP, BSTEP);
        aP0 += 2 * ASTEP; aP1 += 2 * ASTEP; aP2 += 2 * ASTEP;
        bP0 += 2 * BSTEP; bP1 += 2 * BSTEP; bP2 += 2 * BSTEP; bP3 += 2 * BSTEP; bP4 += 2 * BSTEP;
    }
    MFMA_SET(aA0, aA1, aA2, bA0, bA1, bA2, bA3, bA4);
    MFMA_SET(aB0, aB1, aB2, bB0, bB1, bB2, bB3, bB4);
#undef LOAD_SET
#undef MFMA_SET

    // -------- epilogue: LDS transpose (96x320) + tiny W-GEMM + GLU --------
    int rb = (lane >> 4) * 4, cb = lane & 15;

    __syncthreads();
#pragma unroll
    for (int ms = 0; ms < 3; ++ms)
#pragma unroll
        for (int ns = 0; ns < 5; ++ns)
#pragma unroll
            for (int i = 0; i < 4; ++i)
                scr[(wm * 48 + ms * 16 + rb + i) * SCRW + wn * 80 + ns * 16 + cb] = acc[ms][ns][i];
    __syncthreads();

    for (int e = tid; e < BM * 10; e += 512) {
        int row = e % BM;
        int bwl = e / BM;            // 0..9
        int bw = nh * 10 + bwl;
        long m = m0 + row;
        float g[CC];
#pragma unroll
        for (int c = 0; c < CC; ++c) g[c] = scr[row * SCRW + bwl * 32 + c] * invS;
        float y[64];
#pragma unroll
        for (int o = 0; o < 64; ++o) y[o] = WB[CC * 64 + o];
#pragma unroll
        for (int c = 0; c < CC; ++c) {
            float gv = g[c];
#pragma unroll
            for (int o = 0; o < 64; ++o) y[o] = fmaf(gv, WB[c * 64 + o], y[o]);
        }
        if (MODE == 0) {
            // write X^T frag-native: col = bw*32+c, k = m
            long k32 = m >> 5;
            int kb16 = ((int)(m >> 3) & 3) * 16;
            int kj = (int)(m & 7);
#pragma unroll
            for (int c = 0; c < CC; ++c) {
                float rr = y[c] * (1.f / (1.f + __expf(-y[c + 32])));
                long dst = ((k32 * 40) + (bw * 2 + (c >> 4))) * 512
                         + ((c & 15) + kb16) * 8 + kj;
                outH[dst] = (_Float16)(rr * SX);
            }
        } else {
            if (m < Mvalid) {
                long kk = NN + m;
                long k32 = kk >> 5;
                int kb16 = ((int)(kk >> 3) & 3) * 16;
                int kj = (int)(kk & 7);
                float res[CC];
#pragma unroll
                for (int c = 0; c < CC; ++c) {
                    float rr = y[c] * (1.f / (1.f + __expf(-y[c + 32])));
                    long idx = ((k32 * 40) + (bw * 2 + (c >> 4))) * 512
                             + ((c & 15) + kb16) * 8 + kj;
                    float v1 = (float)x1[idx] * (1.f / SX);
                    float v2 = (float)x2[idx] * (1.f / SX);
                    res[c] = fmaxf(rr, fmaxf(v1, v2));
                }
                float4* op = (float4*)(outF + ((long)bw * NN + m) * CC);
#pragma unroll
                for (int qv = 0; qv < CC / 4; ++qv)
                    op[qv] = make_float4(res[qv * 4 + 0], res[qv * 4 + 1],
                                         res[qv * 4 + 2], res[qv * 4 + 3]);
            }
        }
    }
}

extern "C" void kernel_launch(void* const* d_in, const int* in_sizes, int n_in,
                              void* d_out, int out_size, void* d_ws, size_t ws_size,
                              hipStream_t stream)
{
    const float* data = (const float*)d_in[0];
    const float* adj  = (const float*)d_in[1];
    const float* temb = (const float*)d_in[2];
    const float* semb = (const float*)d_in[3];
    const float* W0 = (const float*)d_in[4];
    const float* b0 = (const float*)d_in[5];
    const float* W1 = (const float*)d_in[6];
    const float* b1 = (const float*)d_in[7];
    const float* W2 = (const float*)d_in[8];
    const float* b2 = (const float*)d_in[9];
    float* out = (float*)d_out;
    (void)ws_size; (void)in_sizes; (void)n_in; (void)out_size;

    char* ws = (char*)d_ws;
    _Float16* A16 = (_Float16*)ws;  ws += (size_t)K3 * K3 * 2;        // 302 MB
    _Float16* X0  = (_Float16*)ws;  ws += (size_t)NCOL * K3 * 2;      // 15.7 MB
    _Float16* X1  = (_Float16*)ws;  ws += (size_t)NCOL * K3 * 2;
    _Float16* X2  = (_Float16*)ws;  ws += (size_t)NCOL * K3 * 2;

    k_conv_adj<<<dim3(768, 24), 256, 0, stream>>>(adj, A16);
    k_prep<<<dim3(64, 60), 256, 0, stream>>>(data, temb, semb, X0);

    // layer 1: 128 m-tiles x 2 n-halves = 256 blocks (1/CU, 1 round)
    k_gemm_glu<0><<<256, 512, 0, stream>>>(A16, X0, W0, b0, X1,
                                           nullptr, nullptr, nullptr, 1.f / SA, 0, K3);
    // layer 2
    k_gemm_glu<0><<<256, 512, 0, stream>>>(A16, X1, W1, b1, X2,
                                           nullptr, nullptr, nullptr, 1.f / (SA * SX), 0, K3);
    // layer 3: middle N rows (43 m-tiles x 2), fused GLU + 3-way max + output layout
    k_gemm_glu<1><<<86, 512, 0, stream>>>(A16, X2, W2, b2, nullptr,
                                          X1, X2, out, 1.f / (SA * SX), NN, NN);
}